// Round 8
// baseline (11507.858 us; speedup 1.0000x reference)
//
#include <hip/hip_runtime.h>
#include <math.h>

#define IN_DIM 1024
#define MEM 1024
#define NNODE 2048
#define GX_COLS 5120   // [i|o|f|z|u] blocks of 1024

// ---- scan configuration ----
#define NWG 64           // persistent workgroups, 1/CU guaranteed by VGPR use
#define WGT 512          // 8 waves; wave w owns dims j0=wg*16+2w, j1=j0+1
#define DPW 16           // dims per WG  (MEM / NWG)
#define PUBI (MEM * 2)   // ints per parity in a pub buffer (1024 pairs)

typedef int v4i __attribute__((ext_vector_type(4)));  // asm-input-safe 128b

__device__ __forceinline__ float fsig(float x) {
  return __builtin_amdgcn_rcpf(1.f + __expf(-x));
}
__device__ __forceinline__ float ftanh(float x) {
  // tanh(x) = 1 - 2/(exp(2x)+1); saturates correctly for |x| large
  return 1.f - 2.f * __builtin_amdgcn_rcpf(1.f + __expf(2.f * x));
}

// ---- self-validating packets, system scope (proven in rounds 4/6) ----
// one 16B store publishes BOTH of a wave's dims: (v0, tag, v1, tag)
__device__ __forceinline__ void store_quad(int* p, float v0, float v1, int tg) {
  v4i d;
  d.x = __float_as_int(v0); d.y = tg;
  d.z = __float_as_int(v1); d.w = tg;
  asm volatile("global_store_dwordx4 %0, %1, off sc0 sc1"
               :: "v"(p), "v"(d) : "memory");
}
// poll one producer WG's 16 pairs (128B) until all 16 tags match
__device__ __forceinline__ void poll16(const int* p, int tg, float* dst) {
  v4i a0, a1, a2, a3, a4, a5, a6, a7;
  for (;;) {
    asm volatile(
        "global_load_dwordx4 %0, %8, off sc0 sc1\n\t"
        "global_load_dwordx4 %1, %8, off offset:16 sc0 sc1\n\t"
        "global_load_dwordx4 %2, %8, off offset:32 sc0 sc1\n\t"
        "global_load_dwordx4 %3, %8, off offset:48 sc0 sc1\n\t"
        "global_load_dwordx4 %4, %8, off offset:64 sc0 sc1\n\t"
        "global_load_dwordx4 %5, %8, off offset:80 sc0 sc1\n\t"
        "global_load_dwordx4 %6, %8, off offset:96 sc0 sc1\n\t"
        "global_load_dwordx4 %7, %8, off offset:112 sc0 sc1\n\t"
        "s_waitcnt vmcnt(0)"
        : "=v"(a0), "=v"(a1), "=v"(a2), "=v"(a3),
          "=v"(a4), "=v"(a5), "=v"(a6), "=v"(a7)
        : "v"(p) : "memory");
    if ((((a0.y ^ tg) | (a0.w ^ tg) | (a1.y ^ tg) | (a1.w ^ tg) |
          (a2.y ^ tg) | (a2.w ^ tg) | (a3.y ^ tg) | (a3.w ^ tg) |
          (a4.y ^ tg) | (a4.w ^ tg) | (a5.y ^ tg) | (a5.w ^ tg) |
          (a6.y ^ tg) | (a6.w ^ tg) | (a7.y ^ tg) | (a7.w ^ tg))) == 0)
      break;
    __builtin_amdgcn_s_sleep(1);
  }
  *(float4*)&dst[0]  = make_float4(__int_as_float(a0.x), __int_as_float(a0.z),
                                   __int_as_float(a1.x), __int_as_float(a1.z));
  *(float4*)&dst[4]  = make_float4(__int_as_float(a2.x), __int_as_float(a2.z),
                                   __int_as_float(a3.x), __int_as_float(a3.z));
  *(float4*)&dst[8]  = make_float4(__int_as_float(a4.x), __int_as_float(a4.z),
                                   __int_as_float(a5.x), __int_as_float(a5.z));
  *(float4*)&dst[12] = make_float4(__int_as_float(a6.x), __int_as_float(a6.z),
                                   __int_as_float(a7.x), __int_as_float(a7.z));
}

// ---------------- init: seed the pub buffers ----------------
__global__ void init_ctrl(int* h_pub, int* v_pub) {
  int t = threadIdx.x;
  for (int i = t; i < PUBI / 2; i += blockDim.x) {
    h_pub[2 * i + 0] = 0;            // value 0.0f
    h_pub[2 * i + 1] = 0;            // tag 0   (parity 0 = step-0 input)
    h_pub[PUBI + 2 * i + 0] = 0;
    h_pub[PUBI + 2 * i + 1] = -1;    // parity 1 invalid
  }
  for (int i = t; i < PUBI; i += blockDim.x) {
    v_pub[2 * i + 0] = 0;
    v_pub[2 * i + 1] = -1;           // both parities invalid
  }
}

// ---------------- Gx = inputs @ Wx + bx ----------------
__global__ __launch_bounds__(256) void gemm_gx(
    const float* __restrict__ A, const float* __restrict__ B,
    const float* __restrict__ bias, float* __restrict__ C) {
  __shared__ float As[8][128];
  __shared__ float Bs[8][132];
  const int tid = threadIdx.x;
  const int bm = blockIdx.y * 128;
  const int bn = blockIdx.x * 128;
  const int tx = tid & 15;
  const int ty = tid >> 4;
  const int am = tid >> 1;
  const int ak = (tid & 1) * 4;
  const int bk = tid >> 5;
  const int bn4 = (tid & 31) * 4;

  float acc[8][8] = {};
  for (int k0 = 0; k0 < IN_DIM; k0 += 8) {
    float4 av = *(const float4*)&A[(size_t)(bm + am) * IN_DIM + k0 + ak];
    float4 bv = *(const float4*)&B[(size_t)(k0 + bk) * GX_COLS + bn + bn4];
    __syncthreads();
    As[ak + 0][am] = av.x;
    As[ak + 1][am] = av.y;
    As[ak + 2][am] = av.z;
    As[ak + 3][am] = av.w;
    *(float4*)&Bs[bk][bn4] = bv;
    __syncthreads();
#pragma unroll
    for (int kk = 0; kk < 8; ++kk) {
      float4 a0 = *(const float4*)&As[kk][ty * 4];
      float4 a1 = *(const float4*)&As[kk][64 + ty * 4];
      float4 b0 = *(const float4*)&Bs[kk][tx * 4];
      float4 b1 = *(const float4*)&Bs[kk][64 + tx * 4];
      float a[8] = {a0.x, a0.y, a0.z, a0.w, a1.x, a1.y, a1.z, a1.w};
      float b[8] = {b0.x, b0.y, b0.z, b0.w, b1.x, b1.y, b1.z, b1.w};
#pragma unroll
      for (int i = 0; i < 8; ++i)
#pragma unroll
        for (int j = 0; j < 8; ++j) acc[i][j] += a[i] * b[j];
    }
  }
  float4 bias0 = *(const float4*)&bias[bn + tx * 4];
  float4 bias1 = *(const float4*)&bias[bn + 64 + tx * 4];
#pragma unroll
  for (int i = 0; i < 8; ++i) {
    int row = bm + ((i < 4) ? (ty * 4 + i) : (64 + ty * 4 + (i - 4)));
    float4 c0 = {acc[i][0] + bias0.x, acc[i][1] + bias0.y,
                 acc[i][2] + bias0.z, acc[i][3] + bias0.w};
    float4 c1 = {acc[i][4] + bias1.x, acc[i][5] + bias1.y,
                 acc[i][6] + bias1.z, acc[i][7] + bias1.w};
    *(float4*)&C[(size_t)row * GX_COLS + bn + tx * 4] = c0;
    *(float4*)&C[(size_t)row * GX_COLS + bn + 64 + tx * 4] = c1;
  }
}

// ---------------- persistent chain scan ----------------
// NWG=64, wave w owns dims j0=wg*16+2w, j1=j0+1 (2 dims/wave, K=1024 each).
// __launch_bounds__(512,1) lifts the VGPR cap (was 72 at default occupancy
// target -> compiler re-loaded all 80 weight floats EVERY iteration).
// Wave 1 stages h (lane ln polls producer ln's 128B block); wave 2 stages v.
__global__ __launch_bounds__(WGT, 1) void scan_kernel(
    const float* __restrict__ Wh, const float* __restrict__ bh,
    const float* __restrict__ Wum, const float* __restrict__ bum,
    const float* __restrict__ pic, const float* __restrict__ pfc,
    const float* __restrict__ poc, const float* __restrict__ pzc,
    const float* __restrict__ Gx,
    int* h_pub, int* v_pub,
    float* __restrict__ out) {
  const int wg = blockIdx.x;
  const int tid = threadIdx.x;
  const int w = tid >> 6;    // wave id 0..7
  const int ln = tid & 63;
  const int j0 = wg * DPW + w * 2;   // this wave's two dims

  __shared__ float h_lds[MEM];
  __shared__ float v_lds[MEM];

  // register-resident weight slices for both dims: k = ln*4 + m*256 + e
  float wi[2][16], wo[2][16], wf[2][16], wz[2][16], wu[2][16];
#pragma unroll
  for (int dd = 0; dd < 2; ++dd)
#pragma unroll
    for (int m = 0; m < 4; ++m)
#pragma unroll
      for (int e = 0; e < 4; ++e) {
        int k = ln * 4 + m * 256 + e;
        int j = j0 + dd;
        wi[dd][m * 4 + e] = Wh[(size_t)k * 4096 + 0 * MEM + j];
        wo[dd][m * 4 + e] = Wh[(size_t)k * 4096 + 1 * MEM + j];
        wf[dd][m * 4 + e] = Wh[(size_t)k * 4096 + 2 * MEM + j];
        wz[dd][m * 4 + e] = Wh[(size_t)k * 4096 + 3 * MEM + j];
        wu[dd][m * 4 + e] = Wum[(size_t)k * MEM + j];
      }

  float b_i[2] = {}, b_o[2] = {}, b_f[2] = {}, b_z[2] = {}, b_u[2] = {};
  float p_i[2] = {}, p_f[2] = {}, p_o[2] = {}, p_z[2] = {};
  if (ln == 0) {
#pragma unroll
    for (int dd = 0; dd < 2; ++dd) {
      int j = j0 + dd;
      b_i[dd] = bh[0 * MEM + j]; b_o[dd] = bh[1 * MEM + j];
      b_f[dd] = bh[2 * MEM + j]; b_z[dd] = bh[3 * MEM + j];
      b_u[dd] = bum[j];
      p_i[dd] = pic[j]; p_f[dd] = pfc[j]; p_o[dd] = poc[j]; p_z[dd] = pzc[j];
    }
  }

  float c[2] = {0.f, 0.f}, hmax[2] = {-1e30f, -1e30f};
  float i_keep[2] = {}, f_keep[2] = {}, oh_keep[2] = {}, gux_keep[2] = {};

  for (int t = 0; t < NNODE; ++t) {
    // Gx prefetch: lane 0, float2 covers both dims per gate (issued early)
    float2 g_i = {}, g_o = {}, g_f = {}, g_z = {}, g_u = {};
    if (ln == 0) {
      const float* gx = Gx + (size_t)t * GX_COLS;
      g_i = *(const float2*)&gx[j0];
      g_o = *(const float2*)&gx[MEM + j0];
      g_f = *(const float2*)&gx[2 * MEM + j0];
      g_z = *(const float2*)&gx[3 * MEM + j0];
      g_u = *(const float2*)&gx[4 * MEM + j0];
    }

    // ---- staging window: wave 1 polls h_{t-1} (tag t), 1 producer/lane ----
    if (w == 1)
      poll16(h_pub + (t & 1) * PUBI + ln * 32, t, &h_lds[ln * 16]);
    __syncthreads();                       // BARRIER A: h_lds ready

    float hreg[16];
#pragma unroll
    for (int m = 0; m < 4; ++m)
      *(float4*)&hreg[m * 4] = *(const float4*)&h_lds[m * 256 + ln * 4];

    // ---- early-z: z dots for both dims + reduce + one 16B publish ----
    float sz0 = 0, sz1 = 0;
#pragma unroll
    for (int e = 0; e < 16; ++e) {
      sz0 += hreg[e] * wz[0][e]; sz1 += hreg[e] * wz[1][e];
    }
#pragma unroll
    for (int off = 32; off >= 1; off >>= 1) {
      sz0 += __shfl_down(sz0, off); sz1 += __shfl_down(sz1, off);
    }
    if (ln == 0) {
      float zv0 = fsig(g_z.x + sz0 + b_z[0] + p_z[0] * c[0]);
      float zv1 = fsig(g_z.y + sz1 + b_z[1] + p_z[1] * c[1]);
      store_quad(v_pub + (t & 1) * PUBI + j0 * 2,
                 zv0 * ftanh(c[0]), zv1 * ftanh(c[1]), t + 1);
    }

    // ---- remaining gate dots for both dims ----
    float si0 = 0, si1 = 0, so0 = 0, so1 = 0, sf0 = 0, sf1 = 0;
#pragma unroll
    for (int e = 0; e < 16; ++e) {
      si0 += hreg[e] * wi[0][e]; si1 += hreg[e] * wi[1][e];
      so0 += hreg[e] * wo[0][e]; so1 += hreg[e] * wo[1][e];
      sf0 += hreg[e] * wf[0][e]; sf1 += hreg[e] * wf[1][e];
    }
#pragma unroll
    for (int off = 32; off >= 1; off >>= 1) {
      si0 += __shfl_down(si0, off); si1 += __shfl_down(si1, off);
      so0 += __shfl_down(so0, off); so1 += __shfl_down(so1, off);
      sf0 += __shfl_down(sf0, off); sf1 += __shfl_down(sf1, off);
    }
    if (ln == 0) {
      i_keep[0] = fsig(g_i.x + si0 + b_i[0] + p_i[0] * c[0]);
      i_keep[1] = fsig(g_i.y + si1 + b_i[1] + p_i[1] * c[1]);
      f_keep[0] = fsig(g_f.x + sf0 + b_f[0] + p_f[0] * c[0]);
      f_keep[1] = fsig(g_f.y + sf1 + b_f[1] + p_f[1] * c[1]);
      oh_keep[0] = g_o.x + so0 + b_o[0];
      oh_keep[1] = g_o.y + so1 + b_o[1];
      gux_keep[0] = g_u.x; gux_keep[1] = g_u.y;
    }

    // ---- staging window: wave 2 polls v_t (tag t+1) ----
    if (w == 2)
      poll16(v_pub + (t & 1) * PUBI + ln * 32, t + 1, &v_lds[ln * 16]);
    __syncthreads();                       // BARRIER B: v_lds ready

    float sm0 = 0, sm1 = 0;
#pragma unroll
    for (int m = 0; m < 4; ++m) {
      float4 vv4 = *(const float4*)&v_lds[m * 256 + ln * 4];
      const float* vv = (const float*)&vv4;
#pragma unroll
      for (int e = 0; e < 4; ++e) {
        sm0 += vv[e] * wu[0][m * 4 + e]; sm1 += vv[e] * wu[1][m * 4 + e];
      }
    }
#pragma unroll
    for (int off = 32; off >= 1; off >>= 1) {
      sm0 += __shfl_down(sm0, off); sm1 += __shfl_down(sm1, off);
    }
    if (ln == 0) {
      float uv0 = ftanh(gux_keep[0] + sm0 + b_u[0]);
      float uv1 = ftanh(gux_keep[1] + sm1 + b_u[1]);
      float cn0 = i_keep[0] * uv0 + f_keep[0] * c[0];
      float cn1 = i_keep[1] * uv1 + f_keep[1] * c[1];
      float hn0 = fsig(oh_keep[0] + p_o[0] * cn0) * ftanh(cn0);
      float hn1 = fsig(oh_keep[1] + p_o[1] * cn1) * ftanh(cn1);
      c[0] = cn0; c[1] = cn1;
      store_quad(h_pub + ((t + 1) & 1) * PUBI + j0 * 2, hn0, hn1, t + 1);
      hmax[0] = fmaxf(hmax[0], hn0); hmax[1] = fmaxf(hmax[1], hn1);
    }
  }

  if (ln == 0) { out[j0] = hmax[0]; out[j0 + 1] = hmax[1]; }
}

extern "C" void kernel_launch(void* const* d_in, const int* in_sizes, int n_in,
                              void* d_out, int out_size, void* d_ws, size_t ws_size,
                              hipStream_t stream) {
  const float* inputs = (const float*)d_in[0];
  const float* Wx  = (const float*)d_in[1];
  const float* bx  = (const float*)d_in[2];
  const float* Wh  = (const float*)d_in[3];
  const float* bh  = (const float*)d_in[4];
  const float* Wum = (const float*)d_in[5];
  const float* bum = (const float*)d_in[6];
  const float* pic = (const float*)d_in[7];
  const float* pfc = (const float*)d_in[8];
  const float* poc = (const float*)d_in[9];
  const float* pzc = (const float*)d_in[10];
  float* out = (float*)d_out;

  // ws: Gx (2048*5120 f32) | h_pub (2*PUBI ints) | v_pub (2*PUBI ints)
  float* Gx = (float*)d_ws;
  int* h_pub = (int*)(Gx + (size_t)NNODE * GX_COLS);
  int* v_pub = h_pub + 2 * PUBI;

  init_ctrl<<<1, 256, 0, stream>>>(h_pub, v_pub);
  gemm_gx<<<dim3(GX_COLS / 128, NNODE / 128), 256, 0, stream>>>(inputs, Wx, bx, Gx);
  scan_kernel<<<NWG, WGT, 0, stream>>>(Wh, bh, Wum, bum, pic, pfc, poc, pzc,
                                       Gx, h_pub, v_pub, out);
}

// Round 9
// 9938.319 us; speedup vs baseline: 1.1579x; 1.1579x over previous
//
#include <hip/hip_runtime.h>
#include <math.h>

#define IN_DIM 1024
#define MEM 1024
#define NNODE 2048
#define GX_COLS 5120   // [i|o|f|z|u] blocks of 1024

// ---- scan configuration ----
#define NWG 128          // persistent workgroups (<= 256 CUs -> co-resident)
#define WGT 512          // 8 waves; wave w owns dim j = wg*8+w
#define DPW 8            // dims per WG  (MEM / NWG)
#define PUBI (NWG * 16)  // ints per parity in a pub buffer (128 WGs x 8 pairs)

__device__ __forceinline__ float fsig(float x) {
  return __builtin_amdgcn_rcpf(1.f + __expf(-x));
}
__device__ __forceinline__ float ftanh(float x) {
  // tanh(x) = 1 - 2/(exp(2x)+1); saturates correctly for |x| large
  return 1.f - 2.f * __builtin_amdgcn_rcpf(1.f + __expf(2.f * x));
}

// ---- self-validating 8B packets: (float value, int step-tag) ----
// AGENT scope = sc1 only (LLVM AMDGPU memory model, gfx940+): cross-XCD
// coherence point is the memory-side MALL. sc0+sc1 (rounds 4/6) is SYSTEM
// scope -> DRAM, measured RT ~2800 cyc. This round's single change.
__device__ __forceinline__ void store_pair(int* p, float v, int tg) {
  int2 d; d.x = __float_as_int(v); d.y = tg;
  asm volatile("global_store_dwordx2 %0, %1, off sc1"
               :: "v"(p), "v"(d) : "memory");
}
// poll one producer's 8 pairs (64B) until all tags match; s_sleep backoff
// caps the request rate on the hot lines.
__device__ __forceinline__ void poll_pairs(const int* p, int tg,
                                           float4& lo, float4& hi) {
  int4 a, b, c, d;
  for (;;) {
    asm volatile(
        "global_load_dwordx4 %0, %4, off sc1\n\t"
        "global_load_dwordx4 %1, %4, off offset:16 sc1\n\t"
        "global_load_dwordx4 %2, %4, off offset:32 sc1\n\t"
        "global_load_dwordx4 %3, %4, off offset:48 sc1\n\t"
        "s_waitcnt vmcnt(0)"
        : "=v"(a), "=v"(b), "=v"(c), "=v"(d)
        : "v"(p) : "memory");
    if ((((a.y ^ tg) | (a.w ^ tg) | (b.y ^ tg) | (b.w ^ tg) |
          (c.y ^ tg) | (c.w ^ tg) | (d.y ^ tg) | (d.w ^ tg))) == 0) break;
    __builtin_amdgcn_s_sleep(1);
  }
  lo = make_float4(__int_as_float(a.x), __int_as_float(a.z),
                   __int_as_float(b.x), __int_as_float(b.z));
  hi = make_float4(__int_as_float(c.x), __int_as_float(c.z),
                   __int_as_float(d.x), __int_as_float(d.z));
}

// ---------------- init: seed the pub buffers ----------------
// h parity0 = (0.0, tag 0) [the step-0 input]; h parity1 and all v = tag -1.
__global__ void init_ctrl(int* h_pub, int* v_pub) {
  int t = threadIdx.x;
  for (int i = t; i < PUBI / 2; i += blockDim.x) {
    h_pub[2 * i + 0] = 0;            // value 0.0f
    h_pub[2 * i + 1] = 0;            // tag 0   (parity 0)
    h_pub[PUBI + 2 * i + 0] = 0;
    h_pub[PUBI + 2 * i + 1] = -1;    // parity 1 invalid
  }
  for (int i = t; i < PUBI; i += blockDim.x) {
    v_pub[2 * i + 0] = 0;
    v_pub[2 * i + 1] = -1;           // both parities invalid
  }
}

// ---------------- Gx = inputs @ Wx + bx ----------------
__global__ __launch_bounds__(256) void gemm_gx(
    const float* __restrict__ A, const float* __restrict__ B,
    const float* __restrict__ bias, float* __restrict__ C) {
  __shared__ float As[8][128];
  __shared__ float Bs[8][132];
  const int tid = threadIdx.x;
  const int bm = blockIdx.y * 128;
  const int bn = blockIdx.x * 128;
  const int tx = tid & 15;
  const int ty = tid >> 4;
  const int am = tid >> 1;
  const int ak = (tid & 1) * 4;
  const int bk = tid >> 5;
  const int bn4 = (tid & 31) * 4;

  float acc[8][8] = {};
  for (int k0 = 0; k0 < IN_DIM; k0 += 8) {
    float4 av = *(const float4*)&A[(size_t)(bm + am) * IN_DIM + k0 + ak];
    float4 bv = *(const float4*)&B[(size_t)(k0 + bk) * GX_COLS + bn + bn4];
    __syncthreads();
    As[ak + 0][am] = av.x;
    As[ak + 1][am] = av.y;
    As[ak + 2][am] = av.z;
    As[ak + 3][am] = av.w;
    *(float4*)&Bs[bk][bn4] = bv;
    __syncthreads();
#pragma unroll
    for (int kk = 0; kk < 8; ++kk) {
      float4 a0 = *(const float4*)&As[kk][ty * 4];
      float4 a1 = *(const float4*)&As[kk][64 + ty * 4];
      float4 b0 = *(const float4*)&Bs[kk][tx * 4];
      float4 b1 = *(const float4*)&Bs[kk][64 + tx * 4];
      float a[8] = {a0.x, a0.y, a0.z, a0.w, a1.x, a1.y, a1.z, a1.w};
      float b[8] = {b0.x, b0.y, b0.z, b0.w, b1.x, b1.y, b1.z, b1.w};
#pragma unroll
      for (int i = 0; i < 8; ++i)
#pragma unroll
        for (int j = 0; j < 8; ++j) acc[i][j] += a[i] * b[j];
    }
  }
  float4 bias0 = *(const float4*)&bias[bn + tx * 4];
  float4 bias1 = *(const float4*)&bias[bn + 64 + tx * 4];
#pragma unroll
  for (int i = 0; i < 8; ++i) {
    int row = bm + ((i < 4) ? (ty * 4 + i) : (64 + ty * 4 + (i - 4)));
    float4 c0 = {acc[i][0] + bias0.x, acc[i][1] + bias0.y,
                 acc[i][2] + bias0.z, acc[i][3] + bias0.w};
    float4 c1 = {acc[i][4] + bias1.x, acc[i][5] + bias1.y,
                 acc[i][6] + bias1.z, acc[i][7] + bias1.w};
    *(float4*)&C[(size_t)row * GX_COLS + bn + tx * 4] = c0;
    *(float4*)&C[(size_t)row * GX_COLS + bn + 64 + tx * 4] = c1;
  }
}

// ---------------- persistent chain scan ----------------
// Exact round-6 structure (best known); ONLY the cache-scope bits changed.
// Wave w owns dim j = wg*8+w (in-wave K=1024 reduction, k = ln*4+m*256+e).
// Bounded staging windows: waves 1-2 poll h at loop top, waves 3-4 poll v
// after their gate dots. Direct per-wave publish with early-z. 2 barriers.
__global__ __launch_bounds__(WGT) void scan_kernel(
    const float* __restrict__ Wh, const float* __restrict__ bh,
    const float* __restrict__ Wum, const float* __restrict__ bum,
    const float* __restrict__ pic, const float* __restrict__ pfc,
    const float* __restrict__ poc, const float* __restrict__ pzc,
    const float* __restrict__ Gx,
    int* h_pub, int* v_pub,
    float* __restrict__ out) {
  const int wg = blockIdx.x;
  const int tid = threadIdx.x;
  const int w = tid >> 6;    // wave id == owned local dim
  const int ln = tid & 63;
  const int j = wg * DPW + w;

  __shared__ float h_lds[MEM];
  __shared__ float v_lds[MEM];

  // register-resident weight slices: k = ln*4 + m*256 + e
  float wi[16], wo[16], wf[16], wz[16], wu[16];
#pragma unroll
  for (int m = 0; m < 4; ++m)
#pragma unroll
    for (int e = 0; e < 4; ++e) {
      int k = ln * 4 + m * 256 + e;
      wi[m * 4 + e] = Wh[(size_t)k * 4096 + 0 * MEM + j];
      wo[m * 4 + e] = Wh[(size_t)k * 4096 + 1 * MEM + j];
      wf[m * 4 + e] = Wh[(size_t)k * 4096 + 2 * MEM + j];
      wz[m * 4 + e] = Wh[(size_t)k * 4096 + 3 * MEM + j];
      wu[m * 4 + e] = Wum[(size_t)k * MEM + j];
    }

  float b_i = 0, b_o = 0, b_f = 0, b_z = 0, b_u = 0;
  float p_i = 0, p_f = 0, p_o = 0, p_z = 0;
  if (ln == 0) {
    b_i = bh[0 * MEM + j]; b_o = bh[1 * MEM + j];
    b_f = bh[2 * MEM + j]; b_z = bh[3 * MEM + j];
    b_u = bum[j];
    p_i = pic[j]; p_f = pfc[j]; p_o = poc[j]; p_z = pzc[j];
  }

  float c = 0.f, hmax = -1e30f;
  float i_keep = 0, f_keep = 0, oh_keep = 0, gux_keep = 0;

  for (int t = 0; t < NNODE; ++t) {
    // Gx prefetch: issued first so it overlaps the h poll/barrier
    float gix = 0, gox = 0, gfx = 0, gzx = 0, gux = 0;
    if (ln == 0) {
      const float* gx = Gx + (size_t)t * GX_COLS;
      gix = gx[j]; gox = gx[MEM + j]; gfx = gx[2 * MEM + j];
      gzx = gx[3 * MEM + j]; gux = gx[4 * MEM + j];
    }

    // ---- staging window: waves 1-2 poll+stage h_{t-1} (tag t) ----
    if (w == 1 || w == 2) {
      const int idx = (w - 1) * 64 + ln;   // producer WG 0..127
      float4 lo, hi;
      poll_pairs(h_pub + (t & 1) * PUBI + idx * 16, t, lo, hi);
      *(float4*)&h_lds[idx * 8] = lo;
      *(float4*)&h_lds[idx * 8 + 4] = hi;
    }
    __syncthreads();                       // BARRIER A: h_lds ready

    float hreg[16];
#pragma unroll
    for (int m = 0; m < 4; ++m)
      *(float4*)&hreg[m * 4] = *(const float4*)&h_lds[m * 256 + ln * 4];

    // ---- early-z: z dot + reduce + direct publish of v ----
    float sz = 0;
#pragma unroll
    for (int e = 0; e < 16; ++e) sz += hreg[e] * wz[e];
#pragma unroll
    for (int off = 32; off >= 1; off >>= 1) sz += __shfl_down(sz, off);
    if (ln == 0) {
      float zv = fsig(gzx + sz + b_z + p_z * c);
      float vv = zv * ftanh(c);
      store_pair(v_pub + (t & 1) * PUBI + j * 2, vv, t + 1);
    }

    // ---- remaining gate dots (overlap v propagation) ----
    float si = 0, so = 0, sf = 0;
#pragma unroll
    for (int e = 0; e < 16; ++e) {
      si += hreg[e] * wi[e]; so += hreg[e] * wo[e]; sf += hreg[e] * wf[e];
    }
#pragma unroll
    for (int off = 32; off >= 1; off >>= 1) {
      si += __shfl_down(si, off); so += __shfl_down(so, off);
      sf += __shfl_down(sf, off);
    }
    if (ln == 0) {
      i_keep = fsig(gix + si + b_i + p_i * c);
      f_keep = fsig(gfx + sf + b_f + p_f * c);
      oh_keep = gox + so + b_o;
      gux_keep = gux;
    }

    // ---- staging window: waves 3-4 poll+stage v_t (tag t+1) ----
    if (w == 3 || w == 4) {
      const int idx = (w - 3) * 64 + ln;
      float4 lo, hi;
      poll_pairs(v_pub + (t & 1) * PUBI + idx * 16, t + 1, lo, hi);
      *(float4*)&v_lds[idx * 8] = lo;
      *(float4*)&v_lds[idx * 8 + 4] = hi;
    }
    __syncthreads();                       // BARRIER B: v_lds ready

    float sm = 0;
#pragma unroll
    for (int m = 0; m < 4; ++m) {
      float4 vv4 = *(const float4*)&v_lds[m * 256 + ln * 4];
      const float* vv = (const float*)&vv4;
#pragma unroll
      for (int e = 0; e < 4; ++e) sm += vv[e] * wu[m * 4 + e];
    }
#pragma unroll
    for (int off = 32; off >= 1; off >>= 1) sm += __shfl_down(sm, off);
    if (ln == 0) {
      float uv = ftanh(gux_keep + sm + b_u);
      float cn = i_keep * uv + f_keep * c;
      float ov = fsig(oh_keep + p_o * cn);
      float hn = ov * ftanh(cn);
      c = cn;
      store_pair(h_pub + ((t + 1) & 1) * PUBI + j * 2, hn, t + 1);
      hmax = fmaxf(hmax, hn);
    }
  }

  if (ln == 0) out[j] = hmax;
}

extern "C" void kernel_launch(void* const* d_in, const int* in_sizes, int n_in,
                              void* d_out, int out_size, void* d_ws, size_t ws_size,
                              hipStream_t stream) {
  const float* inputs = (const float*)d_in[0];
  const float* Wx  = (const float*)d_in[1];
  const float* bx  = (const float*)d_in[2];
  const float* Wh  = (const float*)d_in[3];
  const float* bh  = (const float*)d_in[4];
  const float* Wum = (const float*)d_in[5];
  const float* bum = (const float*)d_in[6];
  const float* pic = (const float*)d_in[7];
  const float* pfc = (const float*)d_in[8];
  const float* poc = (const float*)d_in[9];
  const float* pzc = (const float*)d_in[10];
  float* out = (float*)d_out;

  // ws: Gx (2048*5120 f32) | h_pub (2*PUBI ints) | v_pub (2*PUBI ints)
  float* Gx = (float*)d_ws;
  int* h_pub = (int*)(Gx + (size_t)NNODE * GX_COLS);
  int* v_pub = h_pub + 2 * PUBI;

  init_ctrl<<<1, 256, 0, stream>>>(h_pub, v_pub);
  gemm_gx<<<dim3(GX_COLS / 128, NNODE / 128), 256, 0, stream>>>(inputs, Wx, bx, Gx);
  scan_kernel<<<NWG, WGT, 0, stream>>>(Wh, bh, Wum, bum, pic, pfc, poc, pzc,
                                       Gx, h_pub, v_pub, out);
}